// Round 1
// baseline (637.058 us; speedup 1.0000x reference)
//
#include <hip/hip_runtime.h>
#include <hip/hip_bf16.h>
#include <math.h>

// Problem constants
#define B_ 2
#define T_ 2048
#define C_ 2048
#define H_ 16
#define HD_ 128
#define LORA_ 512
#define RD_ 64
#define ND_ 64
#define BT_ (B_*T_)            // 4096
#define NKVA_ 576              // LORA + RD
#define NKVAP_ 640             // padded to 128
#define LOG2_THETA 16.609640474436812f

typedef __bf16 bf16x8 __attribute__((ext_vector_type(8)));
typedef float  f32x4  __attribute__((ext_vector_type(4)));

#define MFMA16(a,b,c) __builtin_amdgcn_mfma_f32_16x16x32_bf16((a),(b),(c),0,0,0)

// ---------------------------------------------------------------- casts
__global__ __launch_bounds__(256) void k_cast_x(const float* __restrict__ x,
                                                __bf16* __restrict__ xb, int n) {
  int idx = blockIdx.x * 256 + threadIdx.x;
  if (idx < n) xb[idx] = (__bf16)x[idx];
}

// dst[n][k] = src[k][n]; src (K,N) f32, dst (NP,K) bf16, zero-fill n in [N,NP)
__global__ __launch_bounds__(256) void k_tcast(const float* __restrict__ src,
                                               __bf16* __restrict__ dst,
                                               int K, int N, int NP) {
  __shared__ float tile[32][33];
  int k0 = blockIdx.x * 32;
  int n0 = blockIdx.y * 32;
  int tx = threadIdx.x & 31, ty = threadIdx.x >> 5;
  for (int i = ty; i < 32; i += 8) {
    int n = n0 + tx;
    tile[i][tx] = (n < N) ? src[(size_t)(k0 + i) * N + n] : 0.0f;
  }
  __syncthreads();
  for (int i = ty; i < 32; i += 8) {
    dst[(size_t)(n0 + i) * K + k0 + tx] = (__bf16)tile[tx][i];
  }
}

// dst[n][kc] = Wo[(kc>>6)*128 + (kc&63)][n]; dst (2048,1024) bf16
__global__ __launch_bounds__(256) void k_tcast_wo(const float* __restrict__ Wo,
                                                  __bf16* __restrict__ dst) {
  __shared__ float tile[32][33];
  int kc0 = blockIdx.x * 32;
  int n0  = blockIdx.y * 32;
  int rbase = (kc0 >> 6) * 128 + (kc0 & 63);
  int tx = threadIdx.x & 31, ty = threadIdx.x >> 5;
  for (int i = ty; i < 32; i += 8)
    tile[i][tx] = Wo[(size_t)(rbase + i) * C_ + n0 + tx];
  __syncthreads();
  for (int i = ty; i < 32; i += 8)
    dst[(size_t)(n0 + i) * 1024 + kc0 + tx] = (__bf16)tile[tx][i];
}

// ---------------------------------------------------------------- GEMM
// C[M][N] (f32) = A[M][K] (bf16, row-major) * B[N][K]^T (bf16, row-major)
// tiles 128x128, BK=32, 256 threads = 4 waves (2x2 of 64x64)
__global__ __launch_bounds__(256) void k_gemm_bt(const __bf16* __restrict__ A,
                                                 const __bf16* __restrict__ B,
                                                 float* __restrict__ C,
                                                 int M, int N, int K) {
  __shared__ __align__(16) __bf16 As[128 * 32];
  __shared__ __align__(16) __bf16 Bs[128 * 32];
  const int tid  = threadIdx.x;
  const int lane = tid & 63;
  const int wave = tid >> 6;
  const int bm = blockIdx.x, bn = blockIdx.y;
  const int r0 = tid >> 2;
  const int c8 = (tid & 3) * 8;
  const __bf16* Ag = A + (size_t)(bm * 128 + r0) * K + c8;
  const __bf16* Bg = B + (size_t)(bn * 128 + r0) * K + c8;
  const int wr = (wave >> 1) * 64, wc = (wave & 1) * 64;
  const int fr = lane & 15, fk = (lane >> 4) * 8;
  const f32x4 fzero = {0.f, 0.f, 0.f, 0.f};
  f32x4 acc[4][4];
#pragma unroll
  for (int i = 0; i < 4; ++i)
#pragma unroll
    for (int j = 0; j < 4; ++j) acc[i][j] = fzero;

  bf16x8 ra0 = *(const bf16x8*)(Ag);
  bf16x8 ra1 = *(const bf16x8*)(Ag + (size_t)64 * K);
  bf16x8 rb0 = *(const bf16x8*)(Bg);
  bf16x8 rb1 = *(const bf16x8*)(Bg + (size_t)64 * K);

  for (int k0 = 0; k0 < K; k0 += 32) {
    __syncthreads();
    *(bf16x8*)&As[r0 * 32 + c8]        = ra0;
    *(bf16x8*)&As[(r0 + 64) * 32 + c8] = ra1;
    *(bf16x8*)&Bs[r0 * 32 + c8]        = rb0;
    *(bf16x8*)&Bs[(r0 + 64) * 32 + c8] = rb1;
    __syncthreads();
    if (k0 + 32 < K) {
      ra0 = *(const bf16x8*)(Ag + k0 + 32);
      ra1 = *(const bf16x8*)(Ag + (size_t)64 * K + k0 + 32);
      rb0 = *(const bf16x8*)(Bg + k0 + 32);
      rb1 = *(const bf16x8*)(Bg + (size_t)64 * K + k0 + 32);
    }
    bf16x8 af[4], bfg[4];
#pragma unroll
    for (int i = 0; i < 4; ++i) af[i]  = *(const bf16x8*)&As[(wr + i * 16 + fr) * 32 + fk];
#pragma unroll
    for (int j = 0; j < 4; ++j) bfg[j] = *(const bf16x8*)&Bs[(wc + j * 16 + fr) * 32 + fk];
#pragma unroll
    for (int i = 0; i < 4; ++i)
#pragma unroll
      for (int j = 0; j < 4; ++j)
        acc[i][j] = MFMA16(af[i], bfg[j], acc[i][j]);
  }
  const int rbase = (lane >> 4) * 4;
  float* Cb = C + (size_t)(bm * 128 + wr + rbase) * N + bn * 128 + wc + fr;
#pragma unroll
  for (int i = 0; i < 4; ++i)
#pragma unroll
    for (int j = 0; j < 4; ++j)
#pragma unroll
      for (int r = 0; r < 4; ++r)
        Cb[(size_t)(i * 16 + r) * N + j * 16] = acc[i][j][r];
}

// ---------------------------------------------------------------- rope
// q (BT,2048) f32 -> qf [b][h][t][128] bf16, rope on d in [64,128)
__global__ __launch_bounds__(256) void k_rope_q(const float* __restrict__ q,
                                                __bf16* __restrict__ qf) {
  int idx = blockIdx.x * 256 + threadIdx.x;   // over B*H*T*HD = 8388608
  int d  = idx & 127;
  int t  = (idx >> 7) & 2047;
  int bh = idx >> 18;
  int h  = bh & 15, b = bh >> 4;
  const float* qrow = q + ((size_t)(b * T_ + t)) * 2048 + h * 128;
  float v;
  if (d < 64) {
    v = qrow[d];
  } else {
    int i = (d - 64) >> 1;
    float freq = exp2f(-((float)(2 * i) / 64.0f) * LOG2_THETA);
    float ang = (float)t * freq;
    float c = cosf(ang), s = sinf(ang);
    float x0 = qrow[64 + 2 * i], x1 = qrow[64 + 2 * i + 1];
    v = (d & 1) ? (x0 * s + x1 * c) : (x0 * c - x1 * s);
  }
  qf[idx] = (__bf16)v;
}

// ckv (BT,640) f32 cols [512,576) -> krope (BT,64) bf16 with rope
__global__ __launch_bounds__(256) void k_rope_k(const float* __restrict__ ckv,
                                                __bf16* __restrict__ krope) {
  int idx = blockIdx.x * 256 + threadIdx.x;   // over B*T*64 = 262144
  int d = idx & 63;
  int t = (idx >> 6) & 2047;
  int b = idx >> 17;
  const float* src = ckv + ((size_t)(b * T_ + t)) * NKVAP_ + 512;
  int i = d >> 1;
  float freq = exp2f(-((float)(2 * i) / 64.0f) * LOG2_THETA);
  float ang = (float)t * freq;
  float c = cosf(ang), s = sinf(ang);
  float x0 = src[2 * i], x1 = src[2 * i + 1];
  float v = (d & 1) ? (x0 * s + x1 * c) : (x0 * c - x1 * s);
  krope[idx] = (__bf16)v;
}

__global__ __launch_bounds__(256) void k_cast_kvl(const float* __restrict__ ckv,
                                                  __bf16* __restrict__ kvl) {
  int idx = blockIdx.x * 256 + threadIdx.x;   // over BT*512
  int r = idx >> 9, c = idx & 511;
  kvl[idx] = (__bf16)ckv[(size_t)r * NKVAP_ + c];
}

// kv (BT,1024) f32 -> kvb (BT,1024) bf16 and kvT [b][h][d][t] bf16
__global__ __launch_bounds__(256) void k_cast_kv(const float* __restrict__ kv,
                                                 __bf16* __restrict__ kvb,
                                                 __bf16* __restrict__ kvT) {
  int idx = blockIdx.x * 256 + threadIdx.x;   // over BT*1024
  int c = idx & 1023, bt = idx >> 10;
  int b = bt >> 11, t = bt & 2047;
  int h = c >> 6, d = c & 63;
  float v = kv[idx];
  __bf16 bv = (__bf16)v;
  kvb[idx] = bv;
  kvT[(((size_t)(b * H_ + h)) * 64 + d) * T_ + t] = bv;
}

// ---------------------------------------------------------------- attention
// qf [bh][t][128], kvb (BT,1024), krope (BT,64), kvT [bh][64][T] -> yc (BT,1024)
__global__ __launch_bounds__(256) void k_attn(const __bf16* __restrict__ qf,
                                              const __bf16* __restrict__ kvb,
                                              const __bf16* __restrict__ krope,
                                              const __bf16* __restrict__ kvT,
                                              __bf16* __restrict__ yc) {
  const int blk = blockIdx.x;
  const int qt = blk & 31;            // T/64 q-tiles
  const int bh = blk >> 5;
  const int b = bh >> 4, h = bh & 15;
  const int lane = threadIdx.x & 63;
  const int wave = threadIdx.x >> 6;
  const int fr = lane & 15;
  const int fk8 = (lane >> 4) * 8;
  const int rbase = (lane >> 4) * 4;
  const int qrow0 = qt * 64 + wave * 16;

  __shared__ __align__(16) __bf16 Ps[4][16][64];

  const __bf16* qb = qf + ((size_t)bh * T_ + qrow0 + fr) * HD_;
  bf16x8 aq[4];
#pragma unroll
  for (int g = 0; g < 4; ++g) aq[g] = *(const bf16x8*)(qb + g * 32 + fk8);

  const f32x4 fzero = {0.f, 0.f, 0.f, 0.f};
  f32x4 accO[4];
#pragma unroll
  for (int g = 0; g < 4; ++g) accO[g] = fzero;
  float m_r[4], l_r[4];
#pragma unroll
  for (int r = 0; r < 4; ++r) { m_r[r] = -1e30f; l_r[r] = 0.f; }

  const float scale2 = 1.4426950408889634f / sqrtf(128.0f);

  for (int s0 = 0; s0 < qrow0 + 16; s0 += 64) {
    f32x4 accS[4];
#pragma unroll
    for (int cg = 0; cg < 4; ++cg) accS[cg] = fzero;
#pragma unroll
    for (int cg = 0; cg < 4; ++cg) {
      const int s = s0 + cg * 16 + fr;
      const __bf16* kn = kvb + ((size_t)(b * T_ + s)) * 1024 + h * 64;
      const __bf16* kr = krope + ((size_t)(b * T_ + s)) * 64;
      bf16x8 bk0 = *(const bf16x8*)(kn + fk8);
      bf16x8 bk1 = *(const bf16x8*)(kn + 32 + fk8);
      bf16x8 bk2 = *(const bf16x8*)(kr + fk8);
      bf16x8 bk3 = *(const bf16x8*)(kr + 32 + fk8);
      accS[cg] = MFMA16(aq[0], bk0, accS[cg]);
      accS[cg] = MFMA16(aq[1], bk1, accS[cg]);
      accS[cg] = MFMA16(aq[2], bk2, accS[cg]);
      accS[cg] = MFMA16(aq[3], bk3, accS[cg]);
    }
    // mask + scale + row stats (lane's rows: qrow0+rbase+r ; col: s0+cg*16+fr)
    float sv[4][4];
    float rowmax[4];
#pragma unroll
    for (int r = 0; r < 4; ++r) rowmax[r] = -1e30f;
#pragma unroll
    for (int cg = 0; cg < 4; ++cg) {
      const int key = s0 + cg * 16 + fr;
#pragma unroll
      for (int r = 0; r < 4; ++r) {
        const int qi = qrow0 + rbase + r;
        float v = accS[cg][r] * scale2;
        v = (key <= qi) ? v : -1e30f;
        sv[cg][r] = v;
        rowmax[r] = fmaxf(rowmax[r], v);
      }
    }
#pragma unroll
    for (int off = 1; off < 16; off <<= 1)
#pragma unroll
      for (int r = 0; r < 4; ++r)
        rowmax[r] = fmaxf(rowmax[r], __shfl_xor(rowmax[r], off, 64));
    float alpha[4], rowsum[4];
#pragma unroll
    for (int r = 0; r < 4; ++r) {
      float mn = fmaxf(m_r[r], rowmax[r]);
      alpha[r] = exp2f(m_r[r] - mn);
      m_r[r] = mn;
      rowsum[r] = 0.f;
    }
#pragma unroll
    for (int cg = 0; cg < 4; ++cg)
#pragma unroll
      for (int r = 0; r < 4; ++r) {
        float p = exp2f(sv[cg][r] - m_r[r]);
        rowsum[r] += p;
        Ps[wave][rbase + r][cg * 16 + fr] = (__bf16)p;
      }
#pragma unroll
    for (int off = 1; off < 16; off <<= 1)
#pragma unroll
      for (int r = 0; r < 4; ++r)
        rowsum[r] += __shfl_xor(rowsum[r], off, 64);
#pragma unroll
    for (int r = 0; r < 4; ++r) l_r[r] = l_r[r] * alpha[r] + rowsum[r];
#pragma unroll
    for (int g = 0; g < 4; ++g)
#pragma unroll
      for (int r = 0; r < 4; ++r) accO[g][r] *= alpha[r];
    // PV: P (16x64) from LDS as A-frags; V from kvT (contiguous in s)
#pragma unroll
    for (int ks = 0; ks < 2; ++ks) {
      bf16x8 ap = *(const bf16x8*)&Ps[wave][fr][ks * 32 + fk8];
#pragma unroll
      for (int g = 0; g < 4; ++g) {
        const __bf16* vp = kvT + ((size_t)bh * 64 + g * 16 + fr) * T_ + s0 + ks * 32 + fk8;
        bf16x8 bv = *(const bf16x8*)vp;
        accO[g] = MFMA16(ap, bv, accO[g]);
      }
    }
  }
  // epilogue: yc[(b*T + qi)*1024 + h*64 + col]
#pragma unroll
  for (int g = 0; g < 4; ++g)
#pragma unroll
    for (int r = 0; r < 4; ++r) {
      const int qi = qrow0 + rbase + r;
      float o = accO[g][r] / l_r[r];
      yc[((size_t)(b * T_ + qi)) * 1024 + h * 64 + g * 16 + fr] = (__bf16)o;
    }
}

// ---------------------------------------------------------------- launch
extern "C" void kernel_launch(void* const* d_in, const int* in_sizes, int n_in,
                              void* d_out, int out_size, void* d_ws, size_t ws_size,
                              hipStream_t stream) {
  const float* x    = (const float*)d_in[0];
  const float* Wq   = (const float*)d_in[1];
  const float* Wkva = (const float*)d_in[2];
  const float* Wkvb = (const float*)d_in[3];
  const float* Wo   = (const float*)d_in[4];
  float* out = (float*)d_out;
  char* ws = (char*)d_ws;

  // workspace layout (bytes)
  size_t off = 0;
  __bf16* xb    = (__bf16*)(ws + off); off += (size_t)BT_ * C_ * 2;          // 16.78M
  __bf16* WqT   = (__bf16*)(ws + off); off += (size_t)2048 * 2048 * 2;       // 8.39M
  __bf16* WkvaT = (__bf16*)(ws + off); off += (size_t)NKVAP_ * 2048 * 2;     // 2.62M
  __bf16* WkvbT = (__bf16*)(ws + off); off += (size_t)1024 * 512 * 2;        // 1.05M
  __bf16* WoTc  = (__bf16*)(ws + off); off += (size_t)2048 * 1024 * 2;       // 4.19M
  float*  q     = (float*)(ws + off);  off += (size_t)BT_ * 2048 * 4;        // 33.55M
  float*  ckv   = (float*)(ws + off);  off += (size_t)BT_ * NKVAP_ * 4;      // 10.49M
  __bf16* kvl   = (__bf16*)(ws + off); off += (size_t)BT_ * 512 * 2;         // 4.19M
  __bf16* krope = (__bf16*)(ws + off); off += (size_t)BT_ * 64 * 2;          // 0.52M
  float*  kv    = (float*)(ws + off);  off += (size_t)BT_ * 1024 * 4;        // 16.78M
  __bf16* qfb   = (__bf16*)(ws + off); off += (size_t)B_ * H_ * T_ * HD_ * 2;// 16.78M
  __bf16* kvb   = (__bf16*)(ws + off); off += (size_t)BT_ * 1024 * 2;        // 8.39M
  __bf16* kvT   = (__bf16*)(ws + off); off += (size_t)B_ * H_ * 64 * T_ * 2; // 8.39M
  __bf16* yc    = (__bf16*)(ws + off); off += (size_t)BT_ * 1024 * 2;        // 8.39M
  // total ~140.5 MB

  // 1. casts / transposes
  k_cast_x<<<(BT_ * C_) / 256, 256, 0, stream>>>(x, xb, BT_ * C_);
  k_tcast<<<dim3(2048 / 32, 2048 / 32), 256, 0, stream>>>(Wq, WqT, 2048, 2048, 2048);
  k_tcast<<<dim3(2048 / 32, NKVAP_ / 32), 256, 0, stream>>>(Wkva, WkvaT, 2048, NKVA_, NKVAP_);
  k_tcast<<<dim3(512 / 32, 1024 / 32), 256, 0, stream>>>(Wkvb, WkvbT, 512, 1024, 1024);
  k_tcast_wo<<<dim3(1024 / 32, 2048 / 32), 256, 0, stream>>>(Wo, WoTc);

  // 2. projections
  k_gemm_bt<<<dim3(BT_ / 128, 2048 / 128), 256, 0, stream>>>(xb, WqT, q, BT_, 2048, 2048);
  k_gemm_bt<<<dim3(BT_ / 128, NKVAP_ / 128), 256, 0, stream>>>(xb, WkvaT, ckv, BT_, NKVAP_, 2048);

  // 3. rope + casts
  k_rope_q<<<(B_ * H_ * T_ * HD_) / 256, 256, 0, stream>>>(q, qfb);
  k_rope_k<<<(BT_ * 64) / 256, 256, 0, stream>>>(ckv, krope);
  k_cast_kvl<<<(BT_ * 512) / 256, 256, 0, stream>>>(ckv, kvl);

  // 4. kv up-projection
  k_gemm_bt<<<dim3(BT_ / 128, 1024 / 128), 256, 0, stream>>>(kvl, WkvbT, kv, BT_, 1024, 512);
  k_cast_kv<<<(BT_ * 1024) / 256, 256, 0, stream>>>(kv, kvb, kvT);

  // 5. attention
  k_attn<<<B_ * H_ * (T_ / 64), 256, 0, stream>>>(qfb, kvb, krope, kvT, yc);

  // 6. output projection
  k_gemm_bt<<<dim3(BT_ / 128, 2048 / 128), 256, 0, stream>>>(yc, WoTc, out, BT_, 2048, 1024);
}

// Round 2
// 465.813 us; speedup vs baseline: 1.3676x; 1.3676x over previous
//
#include <hip/hip_runtime.h>
#include <hip/hip_bf16.h>
#include <math.h>

// Problem constants
#define B_ 2
#define T_ 2048
#define C_ 2048
#define H_ 16
#define HD_ 128
#define LORA_ 512
#define RD_ 64
#define ND_ 64
#define BT_ (B_*T_)            // 4096
#define NKVA_ 576              // LORA + RD
#define NKVAP_ 640             // padded to 128
#define LOG2_THETA 16.609640474436812f

typedef __bf16 bf16x8 __attribute__((ext_vector_type(8)));
typedef float  f32x4  __attribute__((ext_vector_type(4)));

#define MFMA16(a,b,c) __builtin_amdgcn_mfma_f32_16x16x32_bf16((a),(b),(c),0,0,0)

// ---------------------------------------------------------------- casts
__global__ __launch_bounds__(256) void k_cast_x(const float* __restrict__ x,
                                                __bf16* __restrict__ xb, int n) {
  int idx = blockIdx.x * 256 + threadIdx.x;
  if (idx < n) xb[idx] = (__bf16)x[idx];
}

// dst[n][k] = src[k][n]; src (K,N) f32, dst (NP,K) bf16, zero-fill n in [N,NP)
__global__ __launch_bounds__(256) void k_tcast(const float* __restrict__ src,
                                               __bf16* __restrict__ dst,
                                               int K, int N, int NP) {
  __shared__ float tile[32][33];
  int k0 = blockIdx.x * 32;
  int n0 = blockIdx.y * 32;
  int tx = threadIdx.x & 31, ty = threadIdx.x >> 5;
  for (int i = ty; i < 32; i += 8) {
    int n = n0 + tx;
    tile[i][tx] = (n < N) ? src[(size_t)(k0 + i) * N + n] : 0.0f;
  }
  __syncthreads();
  for (int i = ty; i < 32; i += 8) {
    dst[(size_t)(n0 + i) * K + k0 + tx] = (__bf16)tile[tx][i];
  }
}

// dst[n][kc] = Wo[(kc>>6)*128 + (kc&63)][n]; dst (2048,1024) bf16
__global__ __launch_bounds__(256) void k_tcast_wo(const float* __restrict__ Wo,
                                                  __bf16* __restrict__ dst) {
  __shared__ float tile[32][33];
  int kc0 = blockIdx.x * 32;
  int n0  = blockIdx.y * 32;
  int rbase = (kc0 >> 6) * 128 + (kc0 & 63);
  int tx = threadIdx.x & 31, ty = threadIdx.x >> 5;
  for (int i = ty; i < 32; i += 8)
    tile[i][tx] = Wo[(size_t)(rbase + i) * C_ + n0 + tx];
  __syncthreads();
  for (int i = ty; i < 32; i += 8)
    dst[(size_t)(n0 + i) * 1024 + kc0 + tx] = (__bf16)tile[tx][i];
}

// ---------------------------------------------------------------- GEMM
// C[M][N] (f32) = A[M][K] (bf16, row-major) * B[N][K]^T (bf16, row-major)
// tiles 128x128, BK=32, 256 threads = 4 waves (2x2 of 64x64)
__global__ __launch_bounds__(256) void k_gemm_bt(const __bf16* __restrict__ A,
                                                 const __bf16* __restrict__ B,
                                                 float* __restrict__ C,
                                                 int M, int N, int K) {
  __shared__ __align__(16) __bf16 As[128 * 32];
  __shared__ __align__(16) __bf16 Bs[128 * 32];
  const int tid  = threadIdx.x;
  const int lane = tid & 63;
  const int wave = tid >> 6;
  const int bm = blockIdx.x, bn = blockIdx.y;
  const int r0 = tid >> 2;
  const int c8 = (tid & 3) * 8;
  const __bf16* Ag = A + (size_t)(bm * 128 + r0) * K + c8;
  const __bf16* Bg = B + (size_t)(bn * 128 + r0) * K + c8;
  const int wr = (wave >> 1) * 64, wc = (wave & 1) * 64;
  const int fr = lane & 15, fk = (lane >> 4) * 8;
  const f32x4 fzero = {0.f, 0.f, 0.f, 0.f};
  f32x4 acc[4][4];
#pragma unroll
  for (int i = 0; i < 4; ++i)
#pragma unroll
    for (int j = 0; j < 4; ++j) acc[i][j] = fzero;

  bf16x8 ra0 = *(const bf16x8*)(Ag);
  bf16x8 ra1 = *(const bf16x8*)(Ag + (size_t)64 * K);
  bf16x8 rb0 = *(const bf16x8*)(Bg);
  bf16x8 rb1 = *(const bf16x8*)(Bg + (size_t)64 * K);

  for (int k0 = 0; k0 < K; k0 += 32) {
    __syncthreads();
    *(bf16x8*)&As[r0 * 32 + c8]        = ra0;
    *(bf16x8*)&As[(r0 + 64) * 32 + c8] = ra1;
    *(bf16x8*)&Bs[r0 * 32 + c8]        = rb0;
    *(bf16x8*)&Bs[(r0 + 64) * 32 + c8] = rb1;
    __syncthreads();
    if (k0 + 32 < K) {
      ra0 = *(const bf16x8*)(Ag + k0 + 32);
      ra1 = *(const bf16x8*)(Ag + (size_t)64 * K + k0 + 32);
      rb0 = *(const bf16x8*)(Bg + k0 + 32);
      rb1 = *(const bf16x8*)(Bg + (size_t)64 * K + k0 + 32);
    }
    bf16x8 af[4], bfg[4];
#pragma unroll
    for (int i = 0; i < 4; ++i) af[i]  = *(const bf16x8*)&As[(wr + i * 16 + fr) * 32 + fk];
#pragma unroll
    for (int j = 0; j < 4; ++j) bfg[j] = *(const bf16x8*)&Bs[(wc + j * 16 + fr) * 32 + fk];
#pragma unroll
    for (int i = 0; i < 4; ++i)
#pragma unroll
      for (int j = 0; j < 4; ++j)
        acc[i][j] = MFMA16(af[i], bfg[j], acc[i][j]);
  }
  const int rbase = (lane >> 4) * 4;
  float* Cb = C + (size_t)(bm * 128 + wr + rbase) * N + bn * 128 + wc + fr;
#pragma unroll
  for (int i = 0; i < 4; ++i)
#pragma unroll
    for (int j = 0; j < 4; ++j)
#pragma unroll
      for (int r = 0; r < 4; ++r)
        Cb[(size_t)(i * 16 + r) * N + j * 16] = acc[i][j][r];
}

// ---------------------------------------------------------------- rope
// q (BT,2048) f32 -> qf [b][h][t][128] bf16, rope on d in [64,128)
__global__ __launch_bounds__(256) void k_rope_q(const float* __restrict__ q,
                                                __bf16* __restrict__ qf) {
  int idx = blockIdx.x * 256 + threadIdx.x;   // over B*H*T*HD = 8388608
  int d  = idx & 127;
  int t  = (idx >> 7) & 2047;
  int bh = idx >> 18;
  int h  = bh & 15, b = bh >> 4;
  const float* qrow = q + ((size_t)(b * T_ + t)) * 2048 + h * 128;
  float v;
  if (d < 64) {
    v = qrow[d];
  } else {
    int i = (d - 64) >> 1;
    float freq = exp2f(-((float)(2 * i) / 64.0f) * LOG2_THETA);
    float ang = (float)t * freq;
    float c = cosf(ang), s = sinf(ang);
    float x0 = qrow[64 + 2 * i], x1 = qrow[64 + 2 * i + 1];
    v = (d & 1) ? (x0 * s + x1 * c) : (x0 * c - x1 * s);
  }
  qf[idx] = (__bf16)v;
}

// ckv (BT,640) f32 cols [512,576) -> kf[bh][t][64+d] bf16 with rope (dup per h)
__global__ __launch_bounds__(256) void k_rope_kf(const float* __restrict__ ckv,
                                                 __bf16* __restrict__ kf) {
  int idx = blockIdx.x * 256 + threadIdx.x;   // over B*H*T*64 = 4194304
  int d = idx & 63;
  int t = (idx >> 6) & 2047;
  int h = (idx >> 17) & 15;
  int b = idx >> 21;
  const float* src = ckv + ((size_t)(b * T_ + t)) * NKVAP_ + 512;
  int i = d >> 1;
  float freq = exp2f(-((float)(2 * i) / 64.0f) * LOG2_THETA);
  float ang = (float)t * freq;
  float c = cosf(ang), s = sinf(ang);
  float x0 = src[2 * i], x1 = src[2 * i + 1];
  float v = (d & 1) ? (x0 * s + x1 * c) : (x0 * c - x1 * s);
  kf[(((size_t)(b * H_ + h)) * T_ + t) * 128 + 64 + d] = (__bf16)v;
}

__global__ __launch_bounds__(256) void k_cast_kvl(const float* __restrict__ ckv,
                                                  __bf16* __restrict__ kvl) {
  int idx = blockIdx.x * 256 + threadIdx.x;   // over BT*512
  int r = idx >> 9, c = idx & 511;
  kvl[idx] = (__bf16)ckv[(size_t)r * NKVAP_ + c];
}

// kv (BT,1024) f32 -> kf[bh][t][0:64] bf16 (nope part)
__global__ __launch_bounds__(256) void k_cast_kf_nope(const float* __restrict__ kv,
                                                      __bf16* __restrict__ kf) {
  int idx = blockIdx.x * 256 + threadIdx.x;   // over BT*1024
  int c = idx & 1023, bt = idx >> 10;
  int b = bt >> 11, t = bt & 2047;
  int h = c >> 6, d = c & 63;
  kf[(((size_t)(b * H_ + h)) * T_ + t) * 128 + d] = (__bf16)kv[idx];
}

// kv (BT,1024) f32 -> kvT [bh][d][t] bf16 via LDS tile transpose
__global__ __launch_bounds__(256) void k_build_kvT(const float* __restrict__ kv,
                                                   __bf16* __restrict__ kvT) {
  __shared__ float tile[64][65];
  const int bh = blockIdx.x;
  const int b = bh >> 4, h = bh & 15;
  const int t0 = blockIdx.y * 64;
  const int tid = threadIdx.x;
  const int i0 = tid >> 4, d4 = (tid & 15) * 4;
#pragma unroll
  for (int p = 0; p < 4; ++p) {
    int i = i0 + p * 16;
    const float* src = kv + ((size_t)(b * T_ + t0 + i)) * 1024 + h * 64 + d4;
    float4 v = *(const float4*)src;
    tile[i][d4] = v.x; tile[i][d4 + 1] = v.y; tile[i][d4 + 2] = v.z; tile[i][d4 + 3] = v.w;
  }
  __syncthreads();
  const int dd = tid >> 2, tc0 = (tid & 3) * 16;
  __bf16 outv[16];
#pragma unroll
  for (int j = 0; j < 16; ++j) outv[j] = (__bf16)tile[tc0 + j][dd];
  __bf16* dst = kvT + ((size_t)(bh * 64 + dd)) * T_ + t0 + tc0;
  *(bf16x8*)dst = *(bf16x8*)&outv[0];
  *(bf16x8*)(dst + 8) = *(bf16x8*)&outv[8];
}

// ---------------------------------------------------------------- attention
// qf [bh][t][128], kf [bh][t][128], kvT [bh][64][T] -> yc (BT,1024)
// block = 4 waves, 128 q-rows (2 subtiles of 16 per wave); K/V staged in LDS.
__global__ __launch_bounds__(256, 2) void k_attn(const __bf16* __restrict__ qf,
                                                 const __bf16* __restrict__ kf,
                                                 const __bf16* __restrict__ kvT,
                                                 __bf16* __restrict__ yc) {
  const int blk = blockIdx.x;          // 512 = 16 qt * 32 bh
  const int bh = blk & 31;
  const int qt = 15 - (blk >> 5);      // heavy tiles first
  const int b = bh >> 4, h = bh & 15;
  const int qbase = qt * 128;
  const int tid = threadIdx.x;
  const int lane = tid & 63, wave = tid >> 6;
  const int fr = lane & 15, fk8 = (lane >> 4) * 8, rbase = (lane >> 4) * 4;

  __shared__ __align__(16) __bf16 Ks[64][136];   // keys x dims(128)
  __shared__ __align__(16) __bf16 VsT[64][72];   // dims x keys
  __shared__ __align__(16) __bf16 Ps[4][16][72]; // per-wave P relayout

  // Q fragments: 2 subtiles of 16 rows per wave
  bf16x8 aq[2][4];
#pragma unroll
  for (int s = 0; s < 2; ++s) {
    const __bf16* qb = qf + ((size_t)bh * T_ + qbase + s * 64 + wave * 16 + fr) * HD_;
#pragma unroll
    for (int g = 0; g < 4; ++g) aq[s][g] = *(const bf16x8*)(qb + g * 32 + fk8);
  }

  const f32x4 fzero = {0.f, 0.f, 0.f, 0.f};
  f32x4 accO[2][4];
  float m_r[2][4], l_r[2][4];
#pragma unroll
  for (int s = 0; s < 2; ++s) {
#pragma unroll
    for (int g = 0; g < 4; ++g) accO[s][g] = fzero;
#pragma unroll
    for (int r = 0; r < 4; ++r) { m_r[s][r] = -1e30f; l_r[s][r] = 0.f; }
  }

  const float scale2 = 1.4426950408889634f / sqrtf(128.0f);
  const int srow = tid >> 4, scol = (tid & 15) * 8;  // Ks staging map
  const int vrow = tid >> 3, vcol = (tid & 7) * 8;   // VsT staging map
  const __bf16* kbh = kf + (size_t)bh * T_ * 128;
  const __bf16* vbh = kvT + (size_t)bh * 64 * T_;

  for (int s0 = 0; s0 <= qbase + 64; s0 += 64) {
    __syncthreads();
#pragma unroll
    for (int p = 0; p < 4; ++p)
      *(bf16x8*)&Ks[srow + p * 16][scol] =
        *(const bf16x8*)(kbh + (size_t)(s0 + srow + p * 16) * 128 + scol);
#pragma unroll
    for (int p = 0; p < 2; ++p)
      *(bf16x8*)&VsT[vrow + p * 32][vcol] =
        *(const bf16x8*)(vbh + (size_t)(vrow + p * 32) * T_ + s0 + vcol);
    __syncthreads();

    const bool act0 = (s0 <= qbase);   // sub1 always active within loop bound

    // QK^T: K-fragments shared across both q-subtiles
    f32x4 accS[2][4];
#pragma unroll
    for (int s = 0; s < 2; ++s)
#pragma unroll
      for (int cg = 0; cg < 4; ++cg) accS[s][cg] = fzero;
#pragma unroll
    for (int cg = 0; cg < 4; ++cg) {
      bf16x8 bk[4];
#pragma unroll
      for (int kg = 0; kg < 4; ++kg)
        bk[kg] = *(const bf16x8*)&Ks[cg * 16 + fr][kg * 32 + fk8];
      if (act0) {
#pragma unroll
        for (int kg = 0; kg < 4; ++kg)
          accS[0][cg] = MFMA16(aq[0][kg], bk[kg], accS[0][cg]);
      }
#pragma unroll
      for (int kg = 0; kg < 4; ++kg)
        accS[1][cg] = MFMA16(aq[1][kg], bk[kg], accS[1][cg]);
    }

    for (int s = act0 ? 0 : 1; s < 2; ++s) {
      const int qrow0 = qbase + s * 64 + wave * 16;
      float sv[4][4], rowmax[4];
#pragma unroll
      for (int r = 0; r < 4; ++r) rowmax[r] = -1e30f;
#pragma unroll
      for (int cg = 0; cg < 4; ++cg) {
        const int key = s0 + cg * 16 + fr;
#pragma unroll
        for (int r = 0; r < 4; ++r) {
          const int qi = qrow0 + rbase + r;
          float v = accS[s][cg][r] * scale2;
          v = (key <= qi) ? v : -1e30f;
          sv[cg][r] = v;
          rowmax[r] = fmaxf(rowmax[r], v);
        }
      }
#pragma unroll
      for (int off = 1; off < 16; off <<= 1)
#pragma unroll
        for (int r = 0; r < 4; ++r)
          rowmax[r] = fmaxf(rowmax[r], __shfl_xor(rowmax[r], off, 64));
      float alpha[4], rowsum[4];
#pragma unroll
      for (int r = 0; r < 4; ++r) {
        float mn = fmaxf(m_r[s][r], rowmax[r]);
        alpha[r] = exp2f(m_r[s][r] - mn);
        m_r[s][r] = mn;
        rowsum[r] = 0.f;
      }
#pragma unroll
      for (int cg = 0; cg < 4; ++cg)
#pragma unroll
        for (int r = 0; r < 4; ++r) {
          float p = exp2f(sv[cg][r] - m_r[s][r]);
          rowsum[r] += p;
          Ps[wave][rbase + r][cg * 16 + fr] = (__bf16)p;
        }
#pragma unroll
      for (int off = 1; off < 16; off <<= 1)
#pragma unroll
        for (int r = 0; r < 4; ++r)
          rowsum[r] += __shfl_xor(rowsum[r], off, 64);
#pragma unroll
      for (int r = 0; r < 4; ++r) l_r[s][r] = l_r[s][r] * alpha[r] + rowsum[r];
#pragma unroll
      for (int g = 0; g < 4; ++g)
#pragma unroll
        for (int r = 0; r < 4; ++r) accO[s][g][r] *= alpha[r];
      // PV from LDS (per-wave Ps; VsT shared)
#pragma unroll
      for (int ks = 0; ks < 2; ++ks) {
        bf16x8 ap = *(const bf16x8*)&Ps[wave][fr][ks * 32 + fk8];
#pragma unroll
        for (int g = 0; g < 4; ++g) {
          bf16x8 bv = *(const bf16x8*)&VsT[g * 16 + fr][ks * 32 + fk8];
          accO[s][g] = MFMA16(ap, bv, accO[s][g]);
        }
      }
    }
  }
  // epilogue
#pragma unroll
  for (int s = 0; s < 2; ++s)
#pragma unroll
    for (int g = 0; g < 4; ++g)
#pragma unroll
      for (int r = 0; r < 4; ++r) {
        const int qi = qbase + s * 64 + wave * 16 + rbase + r;
        float o = accO[s][g][r] / l_r[s][r];
        yc[((size_t)(b * T_ + qi)) * 1024 + h * 64 + g * 16 + fr] = (__bf16)o;
      }
}

// ---------------------------------------------------------------- launch
extern "C" void kernel_launch(void* const* d_in, const int* in_sizes, int n_in,
                              void* d_out, int out_size, void* d_ws, size_t ws_size,
                              hipStream_t stream) {
  const float* x    = (const float*)d_in[0];
  const float* Wq   = (const float*)d_in[1];
  const float* Wkva = (const float*)d_in[2];
  const float* Wkvb = (const float*)d_in[3];
  const float* Wo   = (const float*)d_in[4];
  float* out = (float*)d_out;
  char* ws = (char*)d_ws;

  // workspace layout (bytes)
  size_t off = 0;
  __bf16* xb    = (__bf16*)(ws + off); off += (size_t)BT_ * C_ * 2;          // 16.78M
  __bf16* WqT   = (__bf16*)(ws + off); off += (size_t)2048 * 2048 * 2;       // 8.39M
  __bf16* WkvaT = (__bf16*)(ws + off); off += (size_t)NKVAP_ * 2048 * 2;     // 2.62M
  __bf16* WkvbT = (__bf16*)(ws + off); off += (size_t)1024 * 512 * 2;        // 1.05M
  __bf16* WoTc  = (__bf16*)(ws + off); off += (size_t)2048 * 1024 * 2;       // 4.19M
  float*  q     = (float*)(ws + off);  off += (size_t)BT_ * 2048 * 4;        // 33.55M
  float*  ckv   = (float*)(ws + off);  off += (size_t)BT_ * NKVAP_ * 4;      // 10.49M
  __bf16* kvl   = (__bf16*)(ws + off); off += (size_t)BT_ * 512 * 2;         // 4.19M
  float*  kv    = (float*)(ws + off);  off += (size_t)BT_ * 1024 * 4;        // 16.78M
  __bf16* qfb   = (__bf16*)(ws + off); off += (size_t)B_ * H_ * T_ * HD_ * 2;// 16.78M
  __bf16* yc    = (__bf16*)(ws + off); off += (size_t)BT_ * 1024 * 2;        // 8.39M
  // kf (16.78M) and kvT (8.39M) alias q's 33.55M buffer: q is dead after k_rope_q,
  // and both are written strictly after k_rope_q in stream order.
  __bf16* kfb = (__bf16*)q;
  __bf16* kvT = (__bf16*)((char*)q + (size_t)B_ * H_ * T_ * HD_ * 2);

  // 1. casts / transposes
  k_cast_x<<<(BT_ * C_) / 256, 256, 0, stream>>>(x, xb, BT_ * C_);
  k_tcast<<<dim3(2048 / 32, 2048 / 32), 256, 0, stream>>>(Wq, WqT, 2048, 2048, 2048);
  k_tcast<<<dim3(2048 / 32, NKVAP_ / 32), 256, 0, stream>>>(Wkva, WkvaT, 2048, NKVA_, NKVAP_);
  k_tcast<<<dim3(512 / 32, 1024 / 32), 256, 0, stream>>>(Wkvb, WkvbT, 512, 1024, 1024);
  k_tcast_wo<<<dim3(1024 / 32, 2048 / 32), 256, 0, stream>>>(Wo, WoTc);

  // 2. projections
  k_gemm_bt<<<dim3(BT_ / 128, 2048 / 128), 256, 0, stream>>>(xb, WqT, q, BT_, 2048, 2048);
  k_gemm_bt<<<dim3(BT_ / 128, NKVAP_ / 128), 256, 0, stream>>>(xb, WkvaT, ckv, BT_, NKVAP_, 2048);

  // 3. rope + casts (q buffer dead after k_rope_q)
  k_rope_q<<<(B_ * H_ * T_ * HD_) / 256, 256, 0, stream>>>(q, qfb);
  k_cast_kvl<<<(BT_ * 512) / 256, 256, 0, stream>>>(ckv, kvl);

  // 4. kv up-projection, then pack kf (nope+rope) and kvT
  k_gemm_bt<<<dim3(BT_ / 128, 1024 / 128), 256, 0, stream>>>(kvl, WkvbT, kv, BT_, 1024, 512);
  k_cast_kf_nope<<<(BT_ * 1024) / 256, 256, 0, stream>>>(kv, kfb);
  k_rope_kf<<<(B_ * H_ * T_ * 64) / 256, 256, 0, stream>>>(ckv, kfb);
  k_build_kvT<<<dim3(B_ * H_, T_ / 64), 256, 0, stream>>>(kv, kvT);

  // 5. attention
  k_attn<<<(T_ / 128) * B_ * H_, 256, 0, stream>>>(qfb, kfb, kvT, yc);

  // 6. output projection
  k_gemm_bt<<<dim3(BT_ / 128, 2048 / 128), 256, 0, stream>>>(yc, WoTc, out, BT_, 2048, 1024);
}

// Round 3
// 448.823 us; speedup vs baseline: 1.4194x; 1.0379x over previous
//
#include <hip/hip_runtime.h>
#include <hip/hip_bf16.h>
#include <math.h>

// Problem constants
#define B_ 2
#define T_ 2048
#define C_ 2048
#define H_ 16
#define HD_ 128
#define LORA_ 512
#define RD_ 64
#define ND_ 64
#define BT_ (B_*T_)            // 4096
#define NKVA_ 576              // LORA + RD
#define NKVAP_ 640             // padded to 128
#define LOG2_THETA 16.609640474436812f

typedef __bf16 bf16x8 __attribute__((ext_vector_type(8)));
typedef float  f32x4  __attribute__((ext_vector_type(4)));

#define MFMA16(a,b,c) __builtin_amdgcn_mfma_f32_16x16x32_bf16((a),(b),(c),0,0,0)

// global -> LDS direct 16B copy (lds dest must be wave-uniform base + lane*16)
__device__ static inline void load_lds16(const __bf16* g, __bf16* l) {
  auto* lp = (__attribute__((address_space(3))) char*)(uintptr_t)(l);
  auto* gp = (const __attribute__((address_space(1))) char*)(g);
  __builtin_amdgcn_global_load_lds(gp, lp, 16, 0, 0);
}

// ---------------------------------------------------------------- casts
__global__ __launch_bounds__(256) void k_cast_x(const float* __restrict__ x,
                                                __bf16* __restrict__ xb, int n) {
  int idx = blockIdx.x * 256 + threadIdx.x;
  if (idx < n) xb[idx] = (__bf16)x[idx];
}

// dst[n][k] = src[k][n]; src (K,N) f32, dst (NP,K) bf16, zero-fill n in [N,NP)
__global__ __launch_bounds__(256) void k_tcast(const float* __restrict__ src,
                                               __bf16* __restrict__ dst,
                                               int K, int N, int NP) {
  __shared__ float tile[32][33];
  int k0 = blockIdx.x * 32;
  int n0 = blockIdx.y * 32;
  int tx = threadIdx.x & 31, ty = threadIdx.x >> 5;
  for (int i = ty; i < 32; i += 8) {
    int n = n0 + tx;
    tile[i][tx] = (n < N) ? src[(size_t)(k0 + i) * N + n] : 0.0f;
  }
  __syncthreads();
  for (int i = ty; i < 32; i += 8) {
    dst[(size_t)(n0 + i) * K + k0 + tx] = (__bf16)tile[tx][i];
  }
}

// dst[n][kc] = Wo[(kc>>6)*128 + (kc&63)][n]; dst (2048,1024) bf16
__global__ __launch_bounds__(256) void k_tcast_wo(const float* __restrict__ Wo,
                                                  __bf16* __restrict__ dst) {
  __shared__ float tile[32][33];
  int kc0 = blockIdx.x * 32;
  int n0  = blockIdx.y * 32;
  int rbase = (kc0 >> 6) * 128 + (kc0 & 63);
  int tx = threadIdx.x & 31, ty = threadIdx.x >> 5;
  for (int i = ty; i < 32; i += 8)
    tile[i][tx] = Wo[(size_t)(rbase + i) * C_ + n0 + tx];
  __syncthreads();
  for (int i = ty; i < 32; i += 8)
    dst[(size_t)(n0 + i) * 1024 + kc0 + tx] = (__bf16)tile[tx][i];
}

// ---------------------------------------------------------------- GEMM
// C[M][N] (f32) = A[M][K] (bf16, row-major) * B[N][K]^T (bf16, row-major)
// tiles 128x128, BK=32, 256 threads = 4 waves (2x2 of 64x64)
// m97-style: global_load_lds width=16 staging, 2 barriers per K-iter.
__global__ __launch_bounds__(256) void k_gemm_bt(const __bf16* __restrict__ A,
                                                 const __bf16* __restrict__ B,
                                                 float* __restrict__ C,
                                                 int M, int N, int K) {
  __shared__ __align__(16) __bf16 As[128 * 32];
  __shared__ __align__(16) __bf16 Bs[128 * 32];
  const int tid  = threadIdx.x;
  const int lane = tid & 63;
  const int wave = tid >> 6;
  const int bm = blockIdx.x, bn = blockIdx.y;
  const int r0 = tid >> 2;
  const int c8 = (tid & 3) * 8;
  const __bf16* Ag = A + (size_t)(bm * 128 + r0) * K + c8;
  const __bf16* Bg = B + (size_t)(bn * 128 + r0) * K + c8;
  __bf16* Asl = &As[tid * 8];          // byte offset tid*16: wave base + lane*16
  __bf16* Bsl = &Bs[tid * 8];
  const int wr = (wave >> 1) * 64, wc = (wave & 1) * 64;
  const int fr = lane & 15, fk = (lane >> 4) * 8;
  const f32x4 fzero = {0.f, 0.f, 0.f, 0.f};
  f32x4 acc[4][4];
#pragma unroll
  for (int i = 0; i < 4; ++i)
#pragma unroll
    for (int j = 0; j < 4; ++j) acc[i][j] = fzero;

  for (int k0 = 0; k0 < K; k0 += 32) {
    __syncthreads();
    load_lds16(Ag + k0,                    Asl);
    load_lds16(Ag + (size_t)64 * K + k0,   Asl + 2048);
    load_lds16(Bg + k0,                    Bsl);
    load_lds16(Bg + (size_t)64 * K + k0,   Bsl + 2048);
    __syncthreads();
    bf16x8 af[4], bfg[4];
#pragma unroll
    for (int i = 0; i < 4; ++i) af[i]  = *(const bf16x8*)&As[(wr + i * 16 + fr) * 32 + fk];
#pragma unroll
    for (int j = 0; j < 4; ++j) bfg[j] = *(const bf16x8*)&Bs[(wc + j * 16 + fr) * 32 + fk];
#pragma unroll
    for (int i = 0; i < 4; ++i)
#pragma unroll
      for (int j = 0; j < 4; ++j)
        acc[i][j] = MFMA16(af[i], bfg[j], acc[i][j]);
  }
  const int rbase = (lane >> 4) * 4;
  float* Cb = C + (size_t)(bm * 128 + wr + rbase) * N + bn * 128 + wc + fr;
#pragma unroll
  for (int i = 0; i < 4; ++i)
#pragma unroll
    for (int j = 0; j < 4; ++j)
#pragma unroll
      for (int r = 0; r < 4; ++r)
        Cb[(size_t)(i * 16 + r) * N + j * 16] = acc[i][j][r];
}

// ---------------------------------------------------------------- rope
// q (BT,2048) f32 -> qf [b][h][t][128] bf16, rope on d in [64,128)
__global__ __launch_bounds__(256) void k_rope_q(const float* __restrict__ q,
                                                __bf16* __restrict__ qf) {
  int idx = blockIdx.x * 256 + threadIdx.x;   // over B*H*T*HD = 8388608
  int d  = idx & 127;
  int t  = (idx >> 7) & 2047;
  int bh = idx >> 18;
  int h  = bh & 15, b = bh >> 4;
  const float* qrow = q + ((size_t)(b * T_ + t)) * 2048 + h * 128;
  float v;
  if (d < 64) {
    v = qrow[d];
  } else {
    int i = (d - 64) >> 1;
    float freq = exp2f(-((float)(2 * i) / 64.0f) * LOG2_THETA);
    float ang = (float)t * freq;
    float c = cosf(ang), s = sinf(ang);
    float x0 = qrow[64 + 2 * i], x1 = qrow[64 + 2 * i + 1];
    v = (d & 1) ? (x0 * s + x1 * c) : (x0 * c - x1 * s);
  }
  qf[idx] = (__bf16)v;
}

// ckv (BT,640) f32 cols [512,576) -> kf[bh][t][64+d] bf16 with rope (dup per h)
__global__ __launch_bounds__(256) void k_rope_kf(const float* __restrict__ ckv,
                                                 __bf16* __restrict__ kf) {
  int idx = blockIdx.x * 256 + threadIdx.x;   // over B*H*T*64 = 4194304
  int d = idx & 63;
  int t = (idx >> 6) & 2047;
  int h = (idx >> 17) & 15;
  int b = idx >> 21;
  const float* src = ckv + ((size_t)(b * T_ + t)) * NKVAP_ + 512;
  int i = d >> 1;
  float freq = exp2f(-((float)(2 * i) / 64.0f) * LOG2_THETA);
  float ang = (float)t * freq;
  float c = cosf(ang), s = sinf(ang);
  float x0 = src[2 * i], x1 = src[2 * i + 1];
  float v = (d & 1) ? (x0 * s + x1 * c) : (x0 * c - x1 * s);
  kf[(((size_t)(b * H_ + h)) * T_ + t) * 128 + 64 + d] = (__bf16)v;
}

__global__ __launch_bounds__(256) void k_cast_kvl(const float* __restrict__ ckv,
                                                  __bf16* __restrict__ kvl) {
  int idx = blockIdx.x * 256 + threadIdx.x;   // over BT*512
  int r = idx >> 9, c = idx & 511;
  kvl[idx] = (__bf16)ckv[(size_t)r * NKVAP_ + c];
}

// kv (BT,1024) f32 -> kf[bh][t][0:64] bf16 (nope part)
__global__ __launch_bounds__(256) void k_cast_kf_nope(const float* __restrict__ kv,
                                                      __bf16* __restrict__ kf) {
  int idx = blockIdx.x * 256 + threadIdx.x;   // over BT*1024
  int c = idx & 1023, bt = idx >> 10;
  int b = bt >> 11, t = bt & 2047;
  int h = c >> 6, d = c & 63;
  kf[(((size_t)(b * H_ + h)) * T_ + t) * 128 + d] = (__bf16)kv[idx];
}

// kv (BT,1024) f32 -> kvT [bh][d][t] bf16 via LDS tile transpose
__global__ __launch_bounds__(256) void k_build_kvT(const float* __restrict__ kv,
                                                   __bf16* __restrict__ kvT) {
  __shared__ float tile[64][65];
  const int bh = blockIdx.x;
  const int b = bh >> 4, h = bh & 15;
  const int t0 = blockIdx.y * 64;
  const int tid = threadIdx.x;
  const int i0 = tid >> 4, d4 = (tid & 15) * 4;
#pragma unroll
  for (int p = 0; p < 4; ++p) {
    int i = i0 + p * 16;
    const float* src = kv + ((size_t)(b * T_ + t0 + i)) * 1024 + h * 64 + d4;
    float4 v = *(const float4*)src;
    tile[i][d4] = v.x; tile[i][d4 + 1] = v.y; tile[i][d4 + 2] = v.z; tile[i][d4 + 3] = v.w;
  }
  __syncthreads();
  const int dd = tid >> 2, tc0 = (tid & 3) * 16;
  __bf16 outv[16];
#pragma unroll
  for (int j = 0; j < 16; ++j) outv[j] = (__bf16)tile[tc0 + j][dd];
  __bf16* dst = kvT + ((size_t)(bh * 64 + dd)) * T_ + t0 + tc0;
  *(bf16x8*)dst = *(bf16x8*)&outv[0];
  *(bf16x8*)(dst + 8) = *(bf16x8*)&outv[8];
}

// ---------------------------------------------------------------- attention
// qf [bh][t][128], kf [bh][t][128], kvT [bh][64][T] -> yc (BT,1024)
// block = 4 waves, 128 q-rows (2 subtiles of 16 per wave); K/V staged in LDS.
// NOTE: subtile loop MUST be statically unrolled — a dynamic lower bound
// demotes accS/accO/m_r/l_r to scratch (round-2: 300 MB spill writes).
__global__ __launch_bounds__(256, 2) void k_attn(const __bf16* __restrict__ qf,
                                                 const __bf16* __restrict__ kf,
                                                 const __bf16* __restrict__ kvT,
                                                 __bf16* __restrict__ yc) {
  const int blk = blockIdx.x;          // 512 = 16 qt * 32 bh
  const int bh = blk & 31;
  const int qt = 15 - (blk >> 5);      // heavy tiles first
  const int b = bh >> 4, h = bh & 15;
  const int qbase = qt * 128;
  const int tid = threadIdx.x;
  const int lane = tid & 63, wave = tid >> 6;
  const int fr = lane & 15, fk8 = (lane >> 4) * 8, rbase = (lane >> 4) * 4;

  __shared__ __align__(16) __bf16 Ks[64][136];   // keys x dims(128)
  __shared__ __align__(16) __bf16 VsT[64][72];   // dims x keys
  __shared__ __align__(16) __bf16 Ps[4][16][72]; // per-wave P relayout

  // Q fragments: 2 subtiles of 16 rows per wave
  bf16x8 aq[2][4];
#pragma unroll
  for (int s = 0; s < 2; ++s) {
    const __bf16* qb = qf + ((size_t)bh * T_ + qbase + s * 64 + wave * 16 + fr) * HD_;
#pragma unroll
    for (int g = 0; g < 4; ++g) aq[s][g] = *(const bf16x8*)(qb + g * 32 + fk8);
  }

  const f32x4 fzero = {0.f, 0.f, 0.f, 0.f};
  f32x4 accO[2][4];
  float m_r[2][4], l_r[2][4];
#pragma unroll
  for (int s = 0; s < 2; ++s) {
#pragma unroll
    for (int g = 0; g < 4; ++g) accO[s][g] = fzero;
#pragma unroll
    for (int r = 0; r < 4; ++r) { m_r[s][r] = -1e30f; l_r[s][r] = 0.f; }
  }

  const float scale2 = 1.4426950408889634f / sqrtf(128.0f);
  const int srow = tid >> 4, scol = (tid & 15) * 8;  // Ks staging map
  const int vrow = tid >> 3, vcol = (tid & 7) * 8;   // VsT staging map
  const __bf16* kbh = kf + (size_t)bh * T_ * 128;
  const __bf16* vbh = kvT + (size_t)bh * 64 * T_;

  for (int s0 = 0; s0 <= qbase + 64; s0 += 64) {
    __syncthreads();
#pragma unroll
    for (int p = 0; p < 4; ++p)
      *(bf16x8*)&Ks[srow + p * 16][scol] =
        *(const bf16x8*)(kbh + (size_t)(s0 + srow + p * 16) * 128 + scol);
#pragma unroll
    for (int p = 0; p < 2; ++p)
      *(bf16x8*)&VsT[vrow + p * 32][vcol] =
        *(const bf16x8*)(vbh + (size_t)(vrow + p * 32) * T_ + s0 + vcol);
    __syncthreads();

    const bool act0 = (s0 <= qbase);   // sub1 always active within loop bound

    // QK^T: K-fragments shared across both q-subtiles
    f32x4 accS[2][4];
#pragma unroll
    for (int s = 0; s < 2; ++s)
#pragma unroll
      for (int cg = 0; cg < 4; ++cg) accS[s][cg] = fzero;
#pragma unroll
    for (int cg = 0; cg < 4; ++cg) {
      bf16x8 bk[4];
#pragma unroll
      for (int kg = 0; kg < 4; ++kg)
        bk[kg] = *(const bf16x8*)&Ks[cg * 16 + fr][kg * 32 + fk8];
      if (act0) {
#pragma unroll
        for (int kg = 0; kg < 4; ++kg)
          accS[0][cg] = MFMA16(aq[0][kg], bk[kg], accS[0][cg]);
      }
#pragma unroll
      for (int kg = 0; kg < 4; ++kg)
        accS[1][cg] = MFMA16(aq[1][kg], bk[kg], accS[1][cg]);
    }

#pragma unroll
    for (int s = 0; s < 2; ++s) {
      if (s == 0 && !act0) continue;   // static unroll; runtime guard only
      const int qrow0 = qbase + s * 64 + wave * 16;
      float sv[4][4], rowmax[4];
#pragma unroll
      for (int r = 0; r < 4; ++r) rowmax[r] = -1e30f;
#pragma unroll
      for (int cg = 0; cg < 4; ++cg) {
        const int key = s0 + cg * 16 + fr;
#pragma unroll
        for (int r = 0; r < 4; ++r) {
          const int qi = qrow0 + rbase + r;
          float v = accS[s][cg][r] * scale2;
          v = (key <= qi) ? v : -1e30f;
          sv[cg][r] = v;
          rowmax[r] = fmaxf(rowmax[r], v);
        }
      }
#pragma unroll
      for (int off = 1; off < 16; off <<= 1)
#pragma unroll
        for (int r = 0; r < 4; ++r)
          rowmax[r] = fmaxf(rowmax[r], __shfl_xor(rowmax[r], off, 64));
      float alpha[4], rowsum[4];
#pragma unroll
      for (int r = 0; r < 4; ++r) {
        float mn = fmaxf(m_r[s][r], rowmax[r]);
        alpha[r] = exp2f(m_r[s][r] - mn);
        m_r[s][r] = mn;
        rowsum[r] = 0.f;
      }
#pragma unroll
      for (int cg = 0; cg < 4; ++cg)
#pragma unroll
        for (int r = 0; r < 4; ++r) {
          float p = exp2f(sv[cg][r] - m_r[s][r]);
          rowsum[r] += p;
          Ps[wave][rbase + r][cg * 16 + fr] = (__bf16)p;
        }
#pragma unroll
      for (int off = 1; off < 16; off <<= 1)
#pragma unroll
        for (int r = 0; r < 4; ++r)
          rowsum[r] += __shfl_xor(rowsum[r], off, 64);
#pragma unroll
      for (int r = 0; r < 4; ++r) l_r[s][r] = l_r[s][r] * alpha[r] + rowsum[r];
#pragma unroll
      for (int g = 0; g < 4; ++g)
#pragma unroll
        for (int r = 0; r < 4; ++r) accO[s][g][r] *= alpha[r];
      // PV from LDS (per-wave Ps; VsT shared)
#pragma unroll
      for (int ks = 0; ks < 2; ++ks) {
        bf16x8 ap = *(const bf16x8*)&Ps[wave][fr][ks * 32 + fk8];
#pragma unroll
        for (int g = 0; g < 4; ++g) {
          bf16x8 bv = *(const bf16x8*)&VsT[g * 16 + fr][ks * 32 + fk8];
          accO[s][g] = MFMA16(ap, bv, accO[s][g]);
        }
      }
    }
  }
  // epilogue
#pragma unroll
  for (int s = 0; s < 2; ++s)
#pragma unroll
    for (int g = 0; g < 4; ++g)
#pragma unroll
      for (int r = 0; r < 4; ++r) {
        const int qi = qbase + s * 64 + wave * 16 + rbase + r;
        float o = accO[s][g][r] / l_r[s][r];
        yc[((size_t)(b * T_ + qi)) * 1024 + h * 64 + g * 16 + fr] = (__bf16)o;
      }
}

// ---------------------------------------------------------------- launch
extern "C" void kernel_launch(void* const* d_in, const int* in_sizes, int n_in,
                              void* d_out, int out_size, void* d_ws, size_t ws_size,
                              hipStream_t stream) {
  const float* x    = (const float*)d_in[0];
  const float* Wq   = (const float*)d_in[1];
  const float* Wkva = (const float*)d_in[2];
  const float* Wkvb = (const float*)d_in[3];
  const float* Wo   = (const float*)d_in[4];
  float* out = (float*)d_out;
  char* ws = (char*)d_ws;

  // workspace layout (bytes)
  size_t off = 0;
  __bf16* xb    = (__bf16*)(ws + off); off += (size_t)BT_ * C_ * 2;          // 16.78M
  __bf16* WqT   = (__bf16*)(ws + off); off += (size_t)2048 * 2048 * 2;       // 8.39M
  __bf16* WkvaT = (__bf16*)(ws + off); off += (size_t)NKVAP_ * 2048 * 2;     // 2.62M
  __bf16* WkvbT = (__bf16*)(ws + off); off += (size_t)1024 * 512 * 2;        // 1.05M
  __bf16* WoTc  = (__bf16*)(ws + off); off += (size_t)2048 * 1024 * 2;       // 4.19M
  float*  q     = (float*)(ws + off);  off += (size_t)BT_ * 2048 * 4;        // 33.55M
  float*  ckv   = (float*)(ws + off);  off += (size_t)BT_ * NKVAP_ * 4;      // 10.49M
  __bf16* kvl   = (__bf16*)(ws + off); off += (size_t)BT_ * 512 * 2;         // 4.19M
  float*  kv    = (float*)(ws + off);  off += (size_t)BT_ * 1024 * 4;        // 16.78M
  __bf16* qfb   = (__bf16*)(ws + off); off += (size_t)B_ * H_ * T_ * HD_ * 2;// 16.78M
  __bf16* yc    = (__bf16*)(ws + off); off += (size_t)BT_ * 1024 * 2;        // 8.39M
  // kf (16.78M) and kvT (8.39M) alias q's 33.55M buffer: q is dead after k_rope_q,
  // and both are written strictly after k_rope_q in stream order.
  __bf16* kfb = (__bf16*)q;
  __bf16* kvT = (__bf16*)((char*)q + (size_t)B_ * H_ * T_ * HD_ * 2);

  // 1. casts / transposes
  k_cast_x<<<(BT_ * C_) / 256, 256, 0, stream>>>(x, xb, BT_ * C_);
  k_tcast<<<dim3(2048 / 32, 2048 / 32), 256, 0, stream>>>(Wq, WqT, 2048, 2048, 2048);
  k_tcast<<<dim3(2048 / 32, NKVAP_ / 32), 256, 0, stream>>>(Wkva, WkvaT, 2048, NKVA_, NKVAP_);
  k_tcast<<<dim3(512 / 32, 1024 / 32), 256, 0, stream>>>(Wkvb, WkvbT, 512, 1024, 1024);
  k_tcast_wo<<<dim3(1024 / 32, 2048 / 32), 256, 0, stream>>>(Wo, WoTc);

  // 2. projections
  k_gemm_bt<<<dim3(BT_ / 128, 2048 / 128), 256, 0, stream>>>(xb, WqT, q, BT_, 2048, 2048);
  k_gemm_bt<<<dim3(BT_ / 128, NKVAP_ / 128), 256, 0, stream>>>(xb, WkvaT, ckv, BT_, NKVAP_, 2048);

  // 3. rope + casts (q buffer dead after k_rope_q)
  k_rope_q<<<(B_ * H_ * T_ * HD_) / 256, 256, 0, stream>>>(q, qfb);
  k_cast_kvl<<<(BT_ * 512) / 256, 256, 0, stream>>>(ckv, kvl);

  // 4. kv up-projection, then pack kf (nope+rope) and kvT
  k_gemm_bt<<<dim3(BT_ / 128, 1024 / 128), 256, 0, stream>>>(kvl, WkvbT, kv, BT_, 1024, 512);
  k_cast_kf_nope<<<(BT_ * 1024) / 256, 256, 0, stream>>>(kv, kfb);
  k_rope_kf<<<(B_ * H_ * T_ * 64) / 256, 256, 0, stream>>>(ckv, kfb);
  k_build_kvT<<<dim3(B_ * H_, T_ / 64), 256, 0, stream>>>(kv, kvT);

  // 5. attention
  k_attn<<<(T_ / 128) * B_ * H_, 256, 0, stream>>>(qfb, kfb, kvT, yc);

  // 6. output projection
  k_gemm_bt<<<dim3(BT_ / 128, 2048 / 128), 256, 0, stream>>>(yc, WoTc, out, BT_, 2048, 1024);
}

// Round 4
// 348.278 us; speedup vs baseline: 1.8292x; 1.2887x over previous
//
#include <hip/hip_runtime.h>
#include <hip/hip_bf16.h>
#include <math.h>

// Problem constants
#define B_ 2
#define T_ 2048
#define C_ 2048
#define H_ 16
#define HD_ 128
#define LORA_ 512
#define RD_ 64
#define ND_ 64
#define BT_ (B_*T_)            // 4096
#define NKVA_ 576              // LORA + RD
#define NKVAP_ 640             // padded to 128
#define LOG2_THETA 16.609640474436812f

typedef __bf16 bf16x8 __attribute__((ext_vector_type(8)));
typedef float  f32x4  __attribute__((ext_vector_type(4)));

#define MFMA16(a,b,c) __builtin_amdgcn_mfma_f32_16x16x32_bf16((a),(b),(c),0,0,0)

// global -> LDS direct 16B copy (lds dest must be wave-uniform base + lane*16)
__device__ static inline void load_lds16(const __bf16* g, __bf16* l) {
  auto* lp = (__attribute__((address_space(3))) char*)(uintptr_t)(l);
  auto* gp = (const __attribute__((address_space(1))) char*)(g);
  __builtin_amdgcn_global_load_lds(gp, lp, 16, 0, 0);
}

__device__ static inline unsigned pkbf(float a, float b) {
  union { __bf16 h[2]; unsigned u; } v;
  v.h[0] = (__bf16)a; v.h[1] = (__bf16)b;
  return v.u;
}

// ---------------------------------------------------------------- casts
__global__ __launch_bounds__(256) void k_cast_x(const float* __restrict__ x,
                                                __bf16* __restrict__ xb, int n) {
  int idx = blockIdx.x * 256 + threadIdx.x;
  if (idx < n) xb[idx] = (__bf16)x[idx];
}

// dst[n][k] = src[k][n]; src (K,N) f32, dst (NP,K) bf16, zero-fill n in [N,NP)
__global__ __launch_bounds__(256) void k_tcast(const float* __restrict__ src,
                                               __bf16* __restrict__ dst,
                                               int K, int N, int NP) {
  __shared__ float tile[32][33];
  int k0 = blockIdx.x * 32;
  int n0 = blockIdx.y * 32;
  int tx = threadIdx.x & 31, ty = threadIdx.x >> 5;
  for (int i = ty; i < 32; i += 8) {
    int n = n0 + tx;
    tile[i][tx] = (n < N) ? src[(size_t)(k0 + i) * N + n] : 0.0f;
  }
  __syncthreads();
  for (int i = ty; i < 32; i += 8) {
    dst[(size_t)(n0 + i) * K + k0 + tx] = (__bf16)tile[tx][i];
  }
}

// dst[n][kc] = Wo[(kc>>6)*128 + (kc&63)][n]; dst (2048,1024) bf16
__global__ __launch_bounds__(256) void k_tcast_wo(const float* __restrict__ Wo,
                                                  __bf16* __restrict__ dst) {
  __shared__ float tile[32][33];
  int kc0 = blockIdx.x * 32;
  int n0  = blockIdx.y * 32;
  int rbase = (kc0 >> 6) * 128 + (kc0 & 63);
  int tx = threadIdx.x & 31, ty = threadIdx.x >> 5;
  for (int i = ty; i < 32; i += 8)
    tile[i][tx] = Wo[(size_t)(rbase + i) * C_ + n0 + tx];
  __syncthreads();
  for (int i = ty; i < 32; i += 8)
    dst[(size_t)(n0 + i) * 1024 + kc0 + tx] = (__bf16)tile[tx][i];
}

// ---------------------------------------------------------------- GEMM
// C[M][N] (f32) = A[M][K] (bf16, row-major) * B[N][K]^T (bf16, row-major)
// 128x128 tile, BK=32, 4 waves. Double-buffered global_load_lds staging:
// stage(next) issued right after the single per-iter barrier, so the global
// latency overlaps the current tile's ds_read+MFMA work.
__global__ __launch_bounds__(256) void k_gemm_bt(const __bf16* __restrict__ A,
                                                 const __bf16* __restrict__ B,
                                                 float* __restrict__ C,
                                                 int M, int N, int K) {
  __shared__ __align__(16) __bf16 As[2][128 * 32];
  __shared__ __align__(16) __bf16 Bs[2][128 * 32];
  const int tid  = threadIdx.x;
  const int lane = tid & 63;
  const int wave = tid >> 6;
  const int bm = blockIdx.x, bn = blockIdx.y;
  const int r0 = tid >> 2;
  const int c8 = (tid & 3) * 8;
  const __bf16* Ag = A + (size_t)(bm * 128 + r0) * K + c8;
  const __bf16* Bg = B + (size_t)(bn * 128 + r0) * K + c8;
  const int wr = (wave >> 1) * 64, wc = (wave & 1) * 64;
  const int fr = lane & 15, fk = (lane >> 4) * 8;
  const f32x4 fzero = {0.f, 0.f, 0.f, 0.f};
  f32x4 acc[4][4];
#pragma unroll
  for (int i = 0; i < 4; ++i)
#pragma unroll
    for (int j = 0; j < 4; ++j) acc[i][j] = fzero;

  // stage tile 0 into buf 0
  load_lds16(Ag,                  &As[0][tid * 8]);
  load_lds16(Ag + (size_t)64 * K, &As[0][tid * 8 + 2048]);
  load_lds16(Bg,                  &Bs[0][tid * 8]);
  load_lds16(Bg + (size_t)64 * K, &Bs[0][tid * 8 + 2048]);

  int buf = 0;
  for (int k0 = 0; k0 < K; k0 += 32) {
    __syncthreads();   // drains own vmcnt -> buf's staging complete for all
    if (k0 + 32 < K) {
      const int nb = buf ^ 1;
      load_lds16(Ag + k0 + 32,                  &As[nb][tid * 8]);
      load_lds16(Ag + (size_t)64 * K + k0 + 32, &As[nb][tid * 8 + 2048]);
      load_lds16(Bg + k0 + 32,                  &Bs[nb][tid * 8]);
      load_lds16(Bg + (size_t)64 * K + k0 + 32, &Bs[nb][tid * 8 + 2048]);
    }
    bf16x8 af[4], bfg[4];
#pragma unroll
    for (int i = 0; i < 4; ++i) af[i]  = *(const bf16x8*)&As[buf][(wr + i * 16 + fr) * 32 + fk];
#pragma unroll
    for (int j = 0; j < 4; ++j) bfg[j] = *(const bf16x8*)&Bs[buf][(wc + j * 16 + fr) * 32 + fk];
#pragma unroll
    for (int i = 0; i < 4; ++i)
#pragma unroll
      for (int j = 0; j < 4; ++j)
        acc[i][j] = MFMA16(af[i], bfg[j], acc[i][j]);
    buf ^= 1;
  }
  const int rbase = (lane >> 4) * 4;
  float* Cb = C + (size_t)(bm * 128 + wr + rbase) * N + bn * 128 + wc + fr;
#pragma unroll
  for (int i = 0; i < 4; ++i)
#pragma unroll
    for (int j = 0; j < 4; ++j)
#pragma unroll
      for (int r = 0; r < 4; ++r)
        Cb[(size_t)(i * 16 + r) * N + j * 16] = acc[i][j][r];
}

// ---------------------------------------------------------------- rope
// q (BT,2048) f32 -> qf [b][h][t][128] bf16, rope on d in [64,128)
__global__ __launch_bounds__(256) void k_rope_q(const float* __restrict__ q,
                                                __bf16* __restrict__ qf) {
  int idx = blockIdx.x * 256 + threadIdx.x;   // over B*H*T*HD = 8388608
  int d  = idx & 127;
  int t  = (idx >> 7) & 2047;
  int bh = idx >> 18;
  int h  = bh & 15, b = bh >> 4;
  const float* qrow = q + ((size_t)(b * T_ + t)) * 2048 + h * 128;
  float v;
  if (d < 64) {
    v = qrow[d];
  } else {
    int i = (d - 64) >> 1;
    float freq = exp2f(-((float)(2 * i) / 64.0f) * LOG2_THETA);
    float ang = (float)t * freq;
    float c = cosf(ang), s = sinf(ang);
    float x0 = qrow[64 + 2 * i], x1 = qrow[64 + 2 * i + 1];
    v = (d & 1) ? (x0 * s + x1 * c) : (x0 * c - x1 * s);
  }
  qf[idx] = (__bf16)v;
}

// ckv (BT,640) f32 cols [512,576) -> kf[bh][t][64+d] bf16 with rope (dup per h)
__global__ __launch_bounds__(256) void k_rope_kf(const float* __restrict__ ckv,
                                                 __bf16* __restrict__ kf) {
  int idx = blockIdx.x * 256 + threadIdx.x;   // over B*H*T*64 = 4194304
  int d = idx & 63;
  int t = (idx >> 6) & 2047;
  int h = (idx >> 17) & 15;
  int b = idx >> 21;
  const float* src = ckv + ((size_t)(b * T_ + t)) * NKVAP_ + 512;
  int i = d >> 1;
  float freq = exp2f(-((float)(2 * i) / 64.0f) * LOG2_THETA);
  float ang = (float)t * freq;
  float c = cosf(ang), s = sinf(ang);
  float x0 = src[2 * i], x1 = src[2 * i + 1];
  float v = (d & 1) ? (x0 * s + x1 * c) : (x0 * c - x1 * s);
  kf[(((size_t)(b * H_ + h)) * T_ + t) * 128 + 64 + d] = (__bf16)v;
}

__global__ __launch_bounds__(256) void k_cast_kvl(const float* __restrict__ ckv,
                                                  __bf16* __restrict__ kvl) {
  int idx = blockIdx.x * 256 + threadIdx.x;   // over BT*512
  int r = idx >> 9, c = idx & 511;
  kvl[idx] = (__bf16)ckv[(size_t)r * NKVAP_ + c];
}

// kv (BT,1024) f32 -> kf[bh][t][0:64] (nope) AND kvT [bh][d][t], one read of kv
__global__ __launch_bounds__(256) void k_pack_kv(const float* __restrict__ kv,
                                                 __bf16* __restrict__ kf,
                                                 __bf16* __restrict__ kvT) {
  __shared__ float tile[64][65];
  const int bh = blockIdx.x;
  const int b = bh >> 4, h = bh & 15;
  const int t0 = blockIdx.y * 64;
  const int tid = threadIdx.x;
  const int i0 = tid >> 4, d4 = (tid & 15) * 4;
#pragma unroll
  for (int p = 0; p < 4; ++p) {
    int i = i0 + p * 16;
    const float* src = kv + ((size_t)(b * T_ + t0 + i)) * 1024 + h * 64 + d4;
    float4 v = *(const float4*)src;
    tile[i][d4] = v.x; tile[i][d4 + 1] = v.y; tile[i][d4 + 2] = v.z; tile[i][d4 + 3] = v.w;
    union { __bf16 hh[4]; uint2 u; } o;
    o.hh[0] = (__bf16)v.x; o.hh[1] = (__bf16)v.y; o.hh[2] = (__bf16)v.z; o.hh[3] = (__bf16)v.w;
    *(uint2*)(kf + ((size_t)bh * T_ + t0 + i) * 128 + d4) = o.u;
  }
  __syncthreads();
  const int dd = tid >> 2, tc0 = (tid & 3) * 16;
  __bf16 outv[16];
#pragma unroll
  for (int j = 0; j < 16; ++j) outv[j] = (__bf16)tile[tc0 + j][dd];
  __bf16* dst = kvT + ((size_t)(bh * 64 + dd)) * T_ + t0 + tc0;
  *(bf16x8*)dst = *(bf16x8*)&outv[0];
  *(bf16x8*)(dst + 8) = *(bf16x8*)&outv[8];
}

// ---------------------------------------------------------------- attention
// S^T formulation: accST = MFMA(K-frag, Q-frag) -> softmax rows live at
// lane&15; P->PV B-operand transform is register shuffles (no LDS);
// output is O^T (4 consecutive d per reg group -> 8B stores).
// 64 q-rows per block (wave w owns rows qbase+w*16..+15), 1024 blocks.
__global__ __launch_bounds__(256, 4) void k_attn(const __bf16* __restrict__ qf,
                                                 const __bf16* __restrict__ kf,
                                                 const __bf16* __restrict__ kvT,
                                                 __bf16* __restrict__ yc) {
  const int blk = blockIdx.x;          // 1024 = 32 qt * 32 bh
  const int bh = blk & 31;             // bh mod 8 == XCD -> per-XCD L2 locality
  const int qt = 31 - (blk >> 5);      // heavy tiles first
  const int b = bh >> 4, h = bh & 15;
  const int qbase = qt * 64;
  const int tid = threadIdx.x;
  const int lane = tid & 63, wave = tid >> 6;
  const int fr = lane & 15, quad = lane >> 4, fk8 = quad * 8;

  __shared__ __align__(16) __bf16 Ks[64][136];   // keys x dims(128), pad->conflict-free reads
  __shared__ __align__(16) __bf16 VsT[64][72];   // dims x keys

  const int qi = qbase + wave * 16 + fr;         // this lane's q-row
  const __bf16* qb = qf + ((size_t)bh * T_ + qi) * HD_;
  bf16x8 aq[4];
#pragma unroll
  for (int g = 0; g < 4; ++g) aq[g] = *(const bf16x8*)(qb + g * 32 + fk8);

  const f32x4 fzero = {0.f, 0.f, 0.f, 0.f};
  f32x4 accO[4];
#pragma unroll
  for (int g = 0; g < 4; ++g) accO[g] = fzero;
  float m = -1e30f, l = 0.f;

  const float scale2 = 1.4426950408889634f / sqrtf(128.0f);
  const int srow = tid >> 4, scol = (tid & 15) * 8;  // Ks staging map
  const int vrow = tid >> 3, vcol = (tid & 7) * 8;   // VsT staging map
  const __bf16* kbh = kf + (size_t)bh * T_ * 128;
  const __bf16* vbh = kvT + (size_t)bh * 64 * T_;
  const int srcA = (quad & 1) * 32 + fr, srcB = srcA + 16;
  const int hi = quad >> 1;

  for (int s0 = 0; s0 <= qbase; s0 += 64) {
    __syncthreads();
#pragma unroll
    for (int p = 0; p < 4; ++p)
      *(bf16x8*)&Ks[srow + p * 16][scol] =
        *(const bf16x8*)(kbh + (size_t)(s0 + srow + p * 16) * 128 + scol);
#pragma unroll
    for (int p = 0; p < 2; ++p)
      *(bf16x8*)&VsT[vrow + p * 32][vcol] =
        *(const bf16x8*)(vbh + (size_t)(vrow + p * 32) * T_ + s0 + vcol);
    __syncthreads();

    // S^T: rows = keys (quad*4+r), cols = q (fr)
    f32x4 accST[4];
#pragma unroll
    for (int cg = 0; cg < 4; ++cg) accST[cg] = fzero;
#pragma unroll
    for (int cg = 0; cg < 4; ++cg) {
#pragma unroll
      for (int kg = 0; kg < 4; ++kg) {
        bf16x8 bk = *(const bf16x8*)&Ks[cg * 16 + fr][kg * 32 + fk8];
        accST[cg] = MFMA16(bk, aq[kg], accST[cg]);
      }
    }

    // mask + scale in place; local row max over this lane's 16 keys
    float lmax = -1e30f;
#pragma unroll
    for (int cg = 0; cg < 4; ++cg) {
#pragma unroll
      for (int r = 0; r < 4; ++r) {
        const int key = s0 + cg * 16 + quad * 4 + r;
        float v = accST[cg][r] * scale2;
        v = (key <= qi) ? v : -1e30f;
        accST[cg][r] = v;
        lmax = fmaxf(lmax, v);
      }
    }
    lmax = fmaxf(lmax, __shfl_xor(lmax, 16, 64));
    lmax = fmaxf(lmax, __shfl_xor(lmax, 32, 64));
    const float mn = fmaxf(m, lmax);
    const float alpha = exp2f(m - mn);
    m = mn;

    float lsum = 0.f;
    unsigned pk0[4], pk1[4];
#pragma unroll
    for (int cg = 0; cg < 4; ++cg) {
      float p0 = exp2f(accST[cg][0] - m);
      float p1 = exp2f(accST[cg][1] - m);
      float p2 = exp2f(accST[cg][2] - m);
      float p3 = exp2f(accST[cg][3] - m);
      lsum += (p0 + p1) + (p2 + p3);
      pk0[cg] = pkbf(p0, p1);
      pk1[cg] = pkbf(p2, p3);
    }
    lsum += __shfl_xor(lsum, 16, 64);
    lsum += __shfl_xor(lsum, 32, 64);
    l = l * alpha + lsum;
#pragma unroll
    for (int g = 0; g < 4; ++g)
#pragma unroll
      for (int r = 0; r < 4; ++r) accO[g][r] *= alpha;

    // PV: B-operand (P) built from register shuffles
#pragma unroll
    for (int ks = 0; ks < 2; ++ks) {
      int a0 = __shfl((int)pk0[2 * ks], srcA, 64);
      int b0 = __shfl((int)pk0[2 * ks + 1], srcA, 64);
      int a1 = __shfl((int)pk1[2 * ks], srcA, 64);
      int b1 = __shfl((int)pk1[2 * ks + 1], srcA, 64);
      int a2 = __shfl((int)pk0[2 * ks], srcB, 64);
      int b2 = __shfl((int)pk0[2 * ks + 1], srcB, 64);
      int a3 = __shfl((int)pk1[2 * ks], srcB, 64);
      int b3 = __shfl((int)pk1[2 * ks + 1], srcB, 64);
      union { int i[4]; bf16x8 v; } pf;
      pf.i[0] = hi ? b0 : a0;
      pf.i[1] = hi ? b1 : a1;
      pf.i[2] = hi ? b2 : a2;
      pf.i[3] = hi ? b3 : a3;
#pragma unroll
      for (int g = 0; g < 4; ++g) {
        bf16x8 vv = *(const bf16x8*)&VsT[g * 16 + fr][ks * 32 + fk8];
        accO[g] = MFMA16(vv, pf.v, accO[g]);
      }
    }
  }

  // epilogue: O^T -> yc[(b*T+qi)*1024 + h*64 + d], d = g*16 + quad*4 + r
  const float linv = 1.0f / l;
  __bf16* yb = yc + ((size_t)(b * T_ + qi)) * 1024 + h * 64 + quad * 4;
#pragma unroll
  for (int g = 0; g < 4; ++g) {
    union { unsigned u[2]; uint2 v; } o;
    o.u[0] = pkbf(accO[g][0] * linv, accO[g][1] * linv);
    o.u[1] = pkbf(accO[g][2] * linv, accO[g][3] * linv);
    *(uint2*)(yb + g * 16) = o.v;
  }
}

// ---------------------------------------------------------------- launch
extern "C" void kernel_launch(void* const* d_in, const int* in_sizes, int n_in,
                              void* d_out, int out_size, void* d_ws, size_t ws_size,
                              hipStream_t stream) {
  const float* x    = (const float*)d_in[0];
  const float* Wq   = (const float*)d_in[1];
  const float* Wkva = (const float*)d_in[2];
  const float* Wkvb = (const float*)d_in[3];
  const float* Wo   = (const float*)d_in[4];
  float* out = (float*)d_out;
  char* ws = (char*)d_ws;

  // workspace layout (bytes)
  size_t off = 0;
  __bf16* xb    = (__bf16*)(ws + off); off += (size_t)BT_ * C_ * 2;          // 16.78M
  __bf16* WqT   = (__bf16*)(ws + off); off += (size_t)2048 * 2048 * 2;       // 8.39M
  __bf16* WkvaT = (__bf16*)(ws + off); off += (size_t)NKVAP_ * 2048 * 2;     // 2.62M
  __bf16* WkvbT = (__bf16*)(ws + off); off += (size_t)1024 * 512 * 2;        // 1.05M
  __bf16* WoTc  = (__bf16*)(ws + off); off += (size_t)2048 * 1024 * 2;       // 4.19M
  float*  q     = (float*)(ws + off);  off += (size_t)BT_ * 2048 * 4;        // 33.55M
  float*  ckv   = (float*)(ws + off);  off += (size_t)BT_ * NKVAP_ * 4;      // 10.49M
  __bf16* kvl   = (__bf16*)(ws + off); off += (size_t)BT_ * 512 * 2;         // 4.19M
  float*  kv    = (float*)(ws + off);  off += (size_t)BT_ * 1024 * 4;        // 16.78M
  __bf16* qfb   = (__bf16*)(ws + off); off += (size_t)B_ * H_ * T_ * HD_ * 2;// 16.78M
  __bf16* yc    = (__bf16*)(ws + off); off += (size_t)BT_ * 1024 * 2;        // 8.39M
  // kf (16.78M) and kvT (8.39M) alias q's 33.55M buffer: q is dead after k_rope_q,
  // and both are written strictly after k_rope_q in stream order.
  __bf16* kfb = (__bf16*)q;
  __bf16* kvT = (__bf16*)((char*)q + (size_t)B_ * H_ * T_ * HD_ * 2);

  // 1. casts / transposes
  k_cast_x<<<(BT_ * C_) / 256, 256, 0, stream>>>(x, xb, BT_ * C_);
  k_tcast<<<dim3(2048 / 32, 2048 / 32), 256, 0, stream>>>(Wq, WqT, 2048, 2048, 2048);
  k_tcast<<<dim3(2048 / 32, NKVAP_ / 32), 256, 0, stream>>>(Wkva, WkvaT, 2048, NKVA_, NKVAP_);
  k_tcast<<<dim3(512 / 32, 1024 / 32), 256, 0, stream>>>(Wkvb, WkvbT, 512, 1024, 1024);
  k_tcast_wo<<<dim3(1024 / 32, 2048 / 32), 256, 0, stream>>>(Wo, WoTc);

  // 2. projections
  k_gemm_bt<<<dim3(BT_ / 128, 2048 / 128), 256, 0, stream>>>(xb, WqT, q, BT_, 2048, 2048);
  k_gemm_bt<<<dim3(BT_ / 128, NKVAP_ / 128), 256, 0, stream>>>(xb, WkvaT, ckv, BT_, NKVAP_, 2048);

  // 3. rope + casts (q buffer dead after k_rope_q)
  k_rope_q<<<(B_ * H_ * T_ * HD_) / 256, 256, 0, stream>>>(q, qfb);
  k_cast_kvl<<<(BT_ * 512) / 256, 256, 0, stream>>>(ckv, kvl);

  // 4. kv up-projection, then pack kf (nope+rope) and kvT
  k_gemm_bt<<<dim3(BT_ / 128, 1024 / 128), 256, 0, stream>>>(kvl, WkvbT, kv, BT_, 1024, 512);
  k_pack_kv<<<dim3(B_ * H_, T_ / 64), 256, 0, stream>>>(kv, kfb, kvT);
  k_rope_kf<<<(B_ * H_ * T_ * 64) / 256, 256, 0, stream>>>(ckv, kfb);

  // 5. attention (1024 blocks, 64 q-rows each)
  k_attn<<<(T_ / 64) * B_ * H_, 256, 0, stream>>>(qfb, kfb, kvT, yc);

  // 6. output projection
  k_gemm_bt<<<dim3(BT_ / 128, 2048 / 128), 256, 0, stream>>>(yc, WoTc, out, BT_, 2048, 1024);
}